// Round 15
// baseline (375.097 us; speedup 1.0000x reference)
//
#include <hip/hip_runtime.h>
#include <math.h>

#define N_ROWS 8192
#define D_DIM  512
#define C_CLS  100

typedef unsigned short u16;
typedef unsigned int u32;
typedef __attribute__((ext_vector_type(8))) _Float16 half8;
typedef __attribute__((ext_vector_type(4))) float floatx4;

// ---------------- ws layout (float offsets), ~31 MB ----------------
#define WS_G      0              // 512*512 fp32 (written by kR)
#define WS_GP     262144         // 32*10*16384 fp32 splitK partials
#define WS_INV    5505024        // 8192
#define WS_WV     5513216        // 8192
#define WS_CLS    5521408        // 8192 (int)
#define WS_CNT    5529600        // 128 (int)
#define WS_U      5538048        // 100*512   (u and v contiguous: zeroed together)
#define WS_V      5589248        // 100*512 = WS_U + 51200
#define WS_ZTH    5640448        // 512*8192 fp16

#define LDA 517                  // kA LDS stride

typedef const __attribute__((address_space(1))) u32* gp32;
typedef __attribute__((address_space(3))) u32* lp32;
__device__ __forceinline__ void cp16(const u16* g, u16* l) {
    __builtin_amdgcn_global_load_lds((gp32)g, (lp32)l, 16, 0, 0);
}

__device__ __forceinline__ u16 f2h(float v) {
    _Float16 h = (_Float16)v;
    return *(u16*)&h;
}

// ===== kA: bx<1024 softmax | [1024,1536) norm+cvt+transpose | [1536,1562) zero ==
__global__ __launch_bounds__(256) void kA(const float* __restrict__ logits,
        const float* __restrict__ x, float* __restrict__ wv, int* __restrict__ cls,
        float* __restrict__ inv, u16* __restrict__ zth,
        int* __restrict__ cnt, float* __restrict__ uvz) {
    __shared__ float xs[16 * LDA];      // 33 KB fp32 stripe (16 rows)
    __shared__ float ns[4][16];
    __shared__ float sv_s[16];
    int bx = blockIdx.x, t = threadIdx.x;
    if (bx < 1024) {
        int lane = t & 63;
        int row0 = (bx << 3) + ((t >> 6) << 1);
        #pragma unroll
        for (int rr = 0; rr < 2; ++rr) {
            int row = row0 + rr;
            const float* lrow = logits + (size_t)row * C_CLS;
            float v1 = lrow[lane];
            bool has2 = (lane + 64) < C_CLS;
            float v2 = has2 ? lrow[lane + 64] : -INFINITY;
            float m; int idx;
            if (v2 > v1) { m = v2; idx = lane + 64; } else { m = v1; idx = lane; }
            #pragma unroll
            for (int off = 32; off >= 1; off >>= 1) {
                float om = __shfl_down(m, off);
                int   oi = __shfl_down(idx, off);
                if (om > m || (om == m && oi < idx)) { m = om; idx = oi; }
            }
            m = __shfl(m, 0);
            idx = __shfl(idx, 0);
            float s = expf(v1 - m) + (has2 ? expf(v2 - m) : 0.0f);
            #pragma unroll
            for (int off = 32; off >= 1; off >>= 1) s += __shfl_down(s, off);
            if (lane == 0) {
                wv[row] = 1.0f / s;
                cls[row] = idx;
            }
        }
        return;
    }
    if (bx >= 1536) {
        int zid = bx - 1536;
        if (zid == 0) {
            if (t < 128) cnt[t] = 0;
        } else {
            int gid = (zid - 1) * 256 + t;      // 0..6399
            float4 z = make_float4(0.f, 0.f, 0.f, 0.f);
            float* p = uvz + (size_t)gid * 16;  // zero u_arr and v_arr (contiguous)
            *(float4*)(p + 0)  = z;
            *(float4*)(p + 4)  = z;
            *(float4*)(p + 8)  = z;
            *(float4*)(p + 12) = z;
        }
        return;
    }
    // -------- 16-row stripe: stage to LDS, norms, fp16 convert + transpose --
    int r0 = (bx - 1024) << 4;
    const float* src = x + (size_t)r0 * D_DIM;
    #pragma unroll
    for (int i = 0; i < 8; ++i) {
        int e = i * 1024 + t * 4;
        int r = e >> 9, c = e & 511;
        *(float4*)&xs[r * LDA + c] = *(const float4*)&src[e];
    }
    __syncthreads();
    {
        int r = t & 15, seg = t >> 4;
        const float* row = &xs[r * LDA + seg * 32];
        float ss = 0.f;
        #pragma unroll
        for (int jj = 0; jj < 32; ++jj) { float v = row[jj]; ss += v * v; }
        ns[0][r] = 0.f;
        __syncthreads();
        atomicAdd(&ns[0][r], ss);
    }
    __syncthreads();
    if (t < 16) {
        float iv = 1.0f / fmaxf(sqrtf(ns[0][t]), 1e-8f);
        inv[r0 + t] = iv;
        sv_s[t] = sqrtf(iv);
    }
    __syncthreads();
    int c = t >> 1, rq = (t & 1) * 8;
    float svl[8];
    #pragma unroll
    for (int ii = 0; ii < 8; ++ii) svl[ii] = sv_s[rq + ii];
    #pragma unroll
    for (int ct = 0; ct < 4; ++ct) {
        int d = ct * 128 + c;
        u16 o[8];
        #pragma unroll
        for (int ii = 0; ii < 8; ++ii)
            o[ii] = f2h(xs[(rq + ii) * LDA + d] * svl[ii]);
        uint4 val = make_uint4((u32)o[0] | ((u32)o[1] << 16),
                               (u32)o[2] | ((u32)o[3] << 16),
                               (u32)o[4] | ((u32)o[5] << 16),
                               (u32)o[6] | ((u32)o[7] << 16));
        *(uint4*)&zth[(size_t)d * N_ROWS + r0 + rq] = val;
    }
}

// ===== kC: blocks 0..319 fp16 GEMM (splitK=32, dbuf); 320..575 atomic-uv ==
__global__ __launch_bounds__(256) void kC(const u16* __restrict__ zth,
        const float* __restrict__ x, const float* __restrict__ inv,
        const float* __restrict__ wv, const int* __restrict__ cls,
        float* __restrict__ Gp, float* __restrict__ u_arr, float* __restrict__ v_arr,
        int* __restrict__ cnt) {
    __shared__ __attribute__((aligned(16))) struct {
        u16 Ah[2][128 * 32], Bh[2][128 * 32];
    } sm;
    int bx = blockIdx.x, t = threadIdx.x;
    if (bx >= 320) {
        // ---- uv: 256 blocks x 32 rows, coalesced stream + global atomics ----
        int row0 = (bx - 320) << 5;
        int w = t >> 6, lane = t & 63;
        #pragma unroll
        for (int rr = 0; rr < 8; ++rr) {
            int m = row0 + w * 8 + rr;
            int c = cls[m];
            float wm = wv[m];
            float wi = wm * inv[m];
            const float4* xr = (const float4*)&x[(size_t)m * D_DIM];
            float* uc = &u_arr[(size_t)c * D_DIM];
            float* vc = &v_arr[(size_t)c * D_DIM];
            #pragma unroll
            for (int q = 0; q < 2; ++q) {
                float4 v4 = xr[lane * 2 + q];
                int base = lane * 8 + q * 4;
                atomicAdd(&uc[base + 0], wi * v4.x);
                atomicAdd(&uc[base + 1], wi * v4.y);
                atomicAdd(&uc[base + 2], wi * v4.z);
                atomicAdd(&uc[base + 3], wi * v4.w);
                atomicAdd(&vc[base + 0], wm * v4.x);
                atomicAdd(&vc[base + 1], wm * v4.y);
                atomicAdd(&vc[base + 2], wm * v4.z);
                atomicAdd(&vc[base + 3], wm * v4.w);
            }
            if (lane == 0) atomicAdd(&cnt[c], 1);
        }
        return;
    }
    int tile = bx % 10;
    int p = bx / 10;                    // 0..31
    int ti = tile < 4 ? 0 : (tile < 7 ? 1 : (tile < 9 ? 2 : 3));
    int tj = tile - (ti == 0 ? 0 : (ti == 1 ? 3 : (ti == 2 ? 5 : 6)));
    int i0 = ti << 7, j0 = tj << 7;
    bool diag = (ti == tj);
    int kb = p << 8;                    // K-chunk of 256
    int w = t >> 6, l = t & 63;
    int srow = t >> 2, scol = (t & 3) << 3;
    int lm = l & 15, lg = l >> 4;
    floatx4 acc[4][4];
    #pragma unroll
    for (int mi = 0; mi < 4; ++mi)
        #pragma unroll
        for (int ni = 0; ni < 4; ++ni) acc[mi][ni] = (floatx4){0.f, 0.f, 0.f, 0.f};
    int d0 = srow * 32 + scol;
    int d1 = (64 + srow) * 32 + scol;
    const size_t ga0 = (size_t)(i0 + srow) * N_ROWS + kb + scol;
    const size_t ga1 = (size_t)(i0 + 64 + srow) * N_ROWS + kb + scol;
    const size_t gb0 = (size_t)(j0 + srow) * N_ROWS + kb + scol;
    const size_t gb1 = (size_t)(j0 + 64 + srow) * N_ROWS + kb + scol;
    cp16(zth + ga0, sm.Ah[0] + d0);
    cp16(zth + ga1, sm.Ah[0] + d1);
    if (!diag) {
        cp16(zth + gb0, sm.Bh[0] + d0);
        cp16(zth + gb1, sm.Bh[0] + d1);
    }
    __syncthreads();
    for (int s = 0; s < 8; ++s) {
        int cur = s & 1, nxt = cur ^ 1;
        if (s + 1 < 8) {
            int ks = (s + 1) << 5;
            cp16(zth + ga0 + ks, sm.Ah[nxt] + d0);
            cp16(zth + ga1 + ks, sm.Ah[nxt] + d1);
            if (!diag) {
                cp16(zth + gb0 + ks, sm.Bh[nxt] + d0);
                cp16(zth + gb1 + ks, sm.Bh[nxt] + d1);
            }
        }
        const u16* Bhs = diag ? sm.Ah[cur] : sm.Bh[cur];
        half8 ah[4], bh[4];
        #pragma unroll
        for (int mi = 0; mi < 4; ++mi) {
            int off = (((w & 1) << 6) + (mi << 4) + lm) * 32 + (lg << 3);
            ah[mi] = *(const half8*)&sm.Ah[cur][off];
        }
        #pragma unroll
        for (int ni = 0; ni < 4; ++ni) {
            int off = (((w >> 1) << 6) + (ni << 4) + lm) * 32 + (lg << 3);
            bh[ni] = *(const half8*)&Bhs[off];
        }
        #pragma unroll
        for (int mi = 0; mi < 4; ++mi)
            #pragma unroll
            for (int ni = 0; ni < 4; ++ni)
                acc[mi][ni] = __builtin_amdgcn_mfma_f32_16x16x32_f16(ah[mi], bh[ni], acc[mi][ni], 0, 0, 0);
        __syncthreads();
    }
    float* Gb = Gp + ((size_t)(p * 10 + tile) << 14);
    #pragma unroll
    for (int mi = 0; mi < 4; ++mi) {
        int row0 = ((w & 1) << 6) + (mi << 4) + (lg << 2);
        #pragma unroll
        for (int ni = 0; ni < 4; ++ni) {
            int col = ((w >> 1) << 6) + (ni << 4) + lm;
            #pragma unroll
            for (int r = 0; r < 4; ++r)
                Gb[(size_t)(row0 + r) * 128 + col] = acc[mi][ni][r];
        }
    }
}

// ===== kR: G[r][c] = sum_p Gp[p][uppertile(r,c)] (mirror lower) =====
__global__ __launch_bounds__(256) void kR(const float* __restrict__ Gp,
                                          float* __restrict__ G) {
    int i = blockIdx.x * 256 + threadIdx.x;      // 0..262143
    int r = i >> 9, c = i & 511;
    int tr = r >> 7, tc = c >> 7, rr = r & 127, cc = c & 127;
    if (tr > tc) { int tmp = tr; tr = tc; tc = tmp; tmp = rr; rr = cc; cc = tmp; }
    int tid = tr * 4 + tc - ((tr * (tr + 1)) >> 1);
    const float* src = Gp + ((size_t)tid << 14) + rr * 128 + cc;
    float s = 0.f;
    #pragma unroll
    for (int p = 0; p < 32; ++p) s += src[(size_t)p * 163840];
    G[i] = s;
}

// ===== kD: protos, tiled for G-reuse: 13 class-groups x 16 col-panels =====
__global__ __launch_bounds__(256) void kD(const float* __restrict__ u_arr,
        const float* __restrict__ v_arr, const int* __restrict__ cnt,
        const float* __restrict__ G, float* __restrict__ out) {
    __shared__ float us[8][512];
    int g = blockIdx.x >> 4;            // 0..12
    int panel = blockIdx.x & 15;        // 0..15
    int t = threadIdx.x;
    for (int idx = t; idx < 8 * 512; idx += 256) {
        int ci = idx >> 9, k = idx & 511;
        int cc = g * 8 + ci;
        us[ci][k] = (cc < C_CLS) ? u_arr[(size_t)cc * D_DIM + k] : 0.f;
    }
    __syncthreads();
    int ci = t >> 5, cj = t & 31;
    int c = g * 8 + ci;
    int j = panel * 32 + cj;
    float acc = 0.f;
    #pragma unroll 8
    for (int k = 0; k < D_DIM; ++k)
        acc += us[ci][k] * G[(size_t)k * D_DIM + j];
    if (c < C_CLS) {
        int n = cnt[c];
        float s = (n > 0) ? 1.0f / (float)n : 0.0f;
        out[(size_t)c * D_DIM + j] = (v_arr[(size_t)c * D_DIM + j] + acc) * s;
    }
}

// ===== kE: inter[i,j,:] = proto[j] - proto[i]; 4 pairs/block =====
__global__ __launch_bounds__(256) void kE(const float* __restrict__ proto,
                                          float* __restrict__ inter) {
    int pair = blockIdx.x * 4 + (threadIdx.x >> 6);
    int i = pair / C_CLS;
    int j = pair - i * C_CLS;
    int d = (threadIdx.x & 63) << 3;
    float4 pj0 = *(const float4*)&proto[j * D_DIM + d];
    float4 pj1 = *(const float4*)&proto[j * D_DIM + d + 4];
    float4 pi0 = *(const float4*)&proto[i * D_DIM + d];
    float4 pi1 = *(const float4*)&proto[i * D_DIM + d + 4];
    float4 r0, r1;
    r0.x = pj0.x - pi0.x; r0.y = pj0.y - pi0.y; r0.z = pj0.z - pi0.z; r0.w = pj0.w - pi0.w;
    r1.x = pj1.x - pi1.x; r1.y = pj1.y - pi1.y; r1.z = pj1.z - pi1.z; r1.w = pj1.w - pi1.w;
    *(float4*)&inter[(size_t)pair * D_DIM + d]     = r0;
    *(float4*)&inter[(size_t)pair * D_DIM + d + 4] = r1;
}

extern "C" void kernel_launch(void* const* d_in, const int* in_sizes, int n_in,
                              void* d_out, int out_size, void* d_ws, size_t ws_size,
                              hipStream_t stream) {
    const float* x      = (const float*)d_in[0];   // [8192, 512]
    const float* logits = (const float*)d_in[1];   // [8192, 100]
    float* out = (float*)d_out;
    float* ws  = (float*)d_ws;
    float* G     = ws + WS_G;
    float* Gp    = ws + WS_GP;
    float* inv   = ws + WS_INV;
    float* wv    = ws + WS_WV;
    int*   cls   = (int*)(ws + WS_CLS);
    int*   cnt   = (int*)(ws + WS_CNT);
    float* u_arr = ws + WS_U;
    float* v_arr = ws + WS_V;
    u16* zth = (u16*)(ws + WS_ZTH);

    kA<<<1562, 256, 0, stream>>>(logits, x, wv, cls, inv, zth, cnt, u_arr);
    kC<<<576, 256, 0, stream>>>(zth, x, inv, wv, cls, Gp, u_arr, v_arr, cnt);
    kR<<<1024, 256, 0, stream>>>(Gp, G);
    kD<<<208, 256, 0, stream>>>(u_arr, v_arr, cnt, G, out);
    kE<<<C_CLS * C_CLS / 4, 256, 0, stream>>>(out, out + C_CLS * D_DIM);
}

// Round 16
// 167.876 us; speedup vs baseline: 2.2344x; 2.2344x over previous
//
#include <hip/hip_runtime.h>
#include <math.h>

#define N_ROWS 8192
#define D_DIM  512
#define C_CLS  100

typedef unsigned short u16;
typedef unsigned int u32;
typedef __attribute__((ext_vector_type(8))) _Float16 half8;
typedef __attribute__((ext_vector_type(4))) float floatx4;

// ---------------- ws layout (float offsets), ~31 MB ----------------
#define WS_G      0              // 512*512 fp32 (written by kR)
#define WS_GP     262144         // 32*10*16384 fp32 splitK partials
#define WS_INV    5505024        // 8192
#define WS_WV     5513216        // 8192
#define WS_CLS    5521408        // 8192 (int)
#define WS_CNT    5529600        // 128 (int)
#define WS_OFFS   5529728        // 128 (int)
#define WS_ORDER  5529856        // 8192 (int)
#define WS_U      5538048        // 100*512
#define WS_V      5589248        // 100*512
#define WS_ZTH    5640448        // 512*8192 fp16

#define LDA 517                  // kA LDS stride

typedef const __attribute__((address_space(1))) u32* gp32;
typedef __attribute__((address_space(3))) u32* lp32;
__device__ __forceinline__ void cp16(const u16* g, u16* l) {
    __builtin_amdgcn_global_load_lds((gp32)g, (lp32)l, 16, 0, 0);
}

__device__ __forceinline__ u16 f2h(float v) {
    _Float16 h = (_Float16)v;
    return *(u16*)&h;
}

// ===== kA: bx<1024 softmax (8 rows) | [1024,1536) norm+cvt+transpose 16 rows =====
__global__ __launch_bounds__(256) void kA(const float* __restrict__ logits,
        const float* __restrict__ x, float* __restrict__ wv, int* __restrict__ cls,
        float* __restrict__ inv, u16* __restrict__ zth) {
    __shared__ float xs[16 * LDA];      // 33 KB fp32 stripe (16 rows)
    __shared__ float ns[4][16];
    __shared__ float sv_s[16];
    int bx = blockIdx.x, t = threadIdx.x;
    if (bx < 1024) {
        int lane = t & 63;
        int row0 = (bx << 3) + ((t >> 6) << 1);
        #pragma unroll
        for (int rr = 0; rr < 2; ++rr) {
            int row = row0 + rr;
            const float* lrow = logits + (size_t)row * C_CLS;
            float v1 = lrow[lane];
            bool has2 = (lane + 64) < C_CLS;
            float v2 = has2 ? lrow[lane + 64] : -INFINITY;
            float m; int idx;
            if (v2 > v1) { m = v2; idx = lane + 64; } else { m = v1; idx = lane; }
            #pragma unroll
            for (int off = 32; off >= 1; off >>= 1) {
                float om = __shfl_down(m, off);
                int   oi = __shfl_down(idx, off);
                if (om > m || (om == m && oi < idx)) { m = om; idx = oi; }
            }
            m = __shfl(m, 0);
            idx = __shfl(idx, 0);
            float s = expf(v1 - m) + (has2 ? expf(v2 - m) : 0.0f);
            #pragma unroll
            for (int off = 32; off >= 1; off >>= 1) s += __shfl_down(s, off);
            if (lane == 0) {
                wv[row] = 1.0f / s;
                cls[row] = idx;
            }
        }
        return;
    }
    // -------- 16-row stripe: stage to LDS, norms, fp16 convert + transpose --
    int r0 = (bx - 1024) << 4;
    const float* src = x + (size_t)r0 * D_DIM;
    #pragma unroll
    for (int i = 0; i < 8; ++i) {
        int e = i * 1024 + t * 4;
        int r = e >> 9, c = e & 511;
        *(float4*)&xs[r * LDA + c] = *(const float4*)&src[e];
    }
    __syncthreads();
    {
        int r = t & 15, seg = t >> 4;
        const float* row = &xs[r * LDA + seg * 32];
        float ss = 0.f;
        #pragma unroll
        for (int jj = 0; jj < 32; ++jj) { float v = row[jj]; ss += v * v; }
        ns[0][r] = 0.f;
        __syncthreads();
        atomicAdd(&ns[0][r], ss);
    }
    __syncthreads();
    if (t < 16) {
        float iv = 1.0f / fmaxf(sqrtf(ns[0][t]), 1e-8f);
        inv[r0 + t] = iv;
        sv_s[t] = sqrtf(iv);
    }
    __syncthreads();
    int c = t >> 1, rq = (t & 1) * 8;
    float svl[8];
    #pragma unroll
    for (int ii = 0; ii < 8; ++ii) svl[ii] = sv_s[rq + ii];
    #pragma unroll
    for (int ct = 0; ct < 4; ++ct) {
        int d = ct * 128 + c;
        u16 o[8];
        #pragma unroll
        for (int ii = 0; ii < 8; ++ii)
            o[ii] = f2h(xs[(rq + ii) * LDA + d] * svl[ii]);
        uint4 val = make_uint4((u32)o[0] | ((u32)o[1] << 16),
                               (u32)o[2] | ((u32)o[3] << 16),
                               (u32)o[4] | ((u32)o[5] << 16),
                               (u32)o[6] | ((u32)o[7] << 16));
        *(uint4*)&zth[(size_t)d * N_ROWS + r0 + rq] = val;
    }
}

// ===== kB: single-block (1024 thr) class histogram + scan + scatter =====
__global__ __launch_bounds__(1024) void kB(const int* __restrict__ cls,
        int* __restrict__ cnt, int* __restrict__ offs, int* __restrict__ order) {
    __shared__ int hist[128], scan_s[128], cur[128];
    int t = threadIdx.x;
    if (t < 128) hist[t] = 0;
    __syncthreads();
    for (int m = t; m < N_ROWS; m += 1024) atomicAdd(&hist[cls[m]], 1);
    __syncthreads();
    if (t < 128) scan_s[t] = hist[t];
    __syncthreads();
    #pragma unroll
    for (int d = 1; d < 128; d <<= 1) {
        int add = (t < 128 && t >= d) ? scan_s[t - d] : 0;
        __syncthreads();
        if (t < 128) scan_s[t] += add;
        __syncthreads();
    }
    if (t < 128) {
        int off0 = scan_s[t] - hist[t];
        cur[t] = off0;
        offs[t] = off0;
        cnt[t] = hist[t];
    }
    __syncthreads();
    for (int m = t; m < N_ROWS; m += 1024) {
        int p = atomicAdd(&cur[cls[m]], 1);
        order[p] = m;
    }
}

// ===== kC: blocks 0..319 fp16 GEMM (splitK=32, dbuf staging); 320..1119 uv ==
__global__ __launch_bounds__(256) void kC(const u16* __restrict__ zth,
        const float* __restrict__ x, const float* __restrict__ inv,
        const float* __restrict__ wv, const int* __restrict__ order,
        const int* __restrict__ offs, const int* __restrict__ cnt,
        float* __restrict__ Gp, float* __restrict__ u_arr, float* __restrict__ v_arr) {
    __shared__ __attribute__((aligned(16))) union {
        struct { u16 Ah[2][128 * 32], Bh[2][128 * 32]; } g;   // 32 KB dbuf
        struct { float us[4][64], vs[4][64]; } uv;
    } sm;
    int bx = blockIdx.x, t = threadIdx.x;
    if (bx >= 320) {
        int idx = bx - 320;
        int c = idx >> 3, jc = idx & 7;
        int g = t >> 6, lane = t & 63;
        int j = jc * 64 + lane;
        int n = cnt[c], o = offs[c];
        float ua = 0.f, va = 0.f;
        for (int p = g; p < n; p += 4) {
            int m = order[o + p];
            float wm = wv[m];
            float wi = wm * inv[m];
            float xv = x[(size_t)m * D_DIM + j];
            ua += wi * xv; va += wm * xv;
        }
        sm.uv.us[g][lane] = ua; sm.uv.vs[g][lane] = va;
        __syncthreads();
        if (g == 0) {
            u_arr[(size_t)c * D_DIM + j] = sm.uv.us[0][lane] + sm.uv.us[1][lane] + sm.uv.us[2][lane] + sm.uv.us[3][lane];
            v_arr[(size_t)c * D_DIM + j] = sm.uv.vs[0][lane] + sm.uv.vs[1][lane] + sm.uv.vs[2][lane] + sm.uv.vs[3][lane];
        }
        return;
    }
    int tile = bx % 10;
    int p = bx / 10;                    // 0..31
    int ti = tile < 4 ? 0 : (tile < 7 ? 1 : (tile < 9 ? 2 : 3));
    int tj = tile - (ti == 0 ? 0 : (ti == 1 ? 3 : (ti == 2 ? 5 : 6)));
    int i0 = ti << 7, j0 = tj << 7;
    bool diag = (ti == tj);
    int kb = p << 8;                    // K-chunk of 256
    int w = t >> 6, l = t & 63;
    int srow = t >> 2, scol = (t & 3) << 3;
    int lm = l & 15, lg = l >> 4;
    floatx4 acc[4][4];
    #pragma unroll
    for (int mi = 0; mi < 4; ++mi)
        #pragma unroll
        for (int ni = 0; ni < 4; ++ni) acc[mi][ni] = (floatx4){0.f, 0.f, 0.f, 0.f};
    int d0 = srow * 32 + scol;
    int d1 = (64 + srow) * 32 + scol;
    const size_t ga0 = (size_t)(i0 + srow) * N_ROWS + kb + scol;
    const size_t ga1 = (size_t)(i0 + 64 + srow) * N_ROWS + kb + scol;
    const size_t gb0 = (size_t)(j0 + srow) * N_ROWS + kb + scol;
    const size_t gb1 = (size_t)(j0 + 64 + srow) * N_ROWS + kb + scol;
    cp16(zth + ga0, sm.g.Ah[0] + d0);
    cp16(zth + ga1, sm.g.Ah[0] + d1);
    if (!diag) {
        cp16(zth + gb0, sm.g.Bh[0] + d0);
        cp16(zth + gb1, sm.g.Bh[0] + d1);
    }
    __syncthreads();
    for (int s = 0; s < 8; ++s) {
        int cur = s & 1, nxt = cur ^ 1;
        if (s + 1 < 8) {
            int ks = (s + 1) << 5;
            cp16(zth + ga0 + ks, sm.g.Ah[nxt] + d0);
            cp16(zth + ga1 + ks, sm.g.Ah[nxt] + d1);
            if (!diag) {
                cp16(zth + gb0 + ks, sm.g.Bh[nxt] + d0);
                cp16(zth + gb1 + ks, sm.g.Bh[nxt] + d1);
            }
        }
        const u16* Bhs = diag ? sm.g.Ah[cur] : sm.g.Bh[cur];
        half8 ah[4], bh[4];
        #pragma unroll
        for (int mi = 0; mi < 4; ++mi) {
            int off = (((w & 1) << 6) + (mi << 4) + lm) * 32 + (lg << 3);
            ah[mi] = *(const half8*)&sm.g.Ah[cur][off];
        }
        #pragma unroll
        for (int ni = 0; ni < 4; ++ni) {
            int off = (((w >> 1) << 6) + (ni << 4) + lm) * 32 + (lg << 3);
            bh[ni] = *(const half8*)&Bhs[off];
        }
        #pragma unroll
        for (int mi = 0; mi < 4; ++mi)
            #pragma unroll
            for (int ni = 0; ni < 4; ++ni)
                acc[mi][ni] = __builtin_amdgcn_mfma_f32_16x16x32_f16(ah[mi], bh[ni], acc[mi][ni], 0, 0, 0);
        __syncthreads();
    }
    float* Gb = Gp + ((size_t)(p * 10 + tile) << 14);
    #pragma unroll
    for (int mi = 0; mi < 4; ++mi) {
        int row0 = ((w & 1) << 6) + (mi << 4) + (lg << 2);
        #pragma unroll
        for (int ni = 0; ni < 4; ++ni) {
            int col = ((w >> 1) << 6) + (ni << 4) + lm;
            #pragma unroll
            for (int r = 0; r < 4; ++r)
                Gb[(size_t)(row0 + r) * 128 + col] = acc[mi][ni][r];
        }
    }
}

// ===== kR: G[r][c] = sum_p Gp[p][uppertile(r,c)] (mirror lower) =====
__global__ __launch_bounds__(256) void kR(const float* __restrict__ Gp,
                                          float* __restrict__ G) {
    int i = blockIdx.x * 256 + threadIdx.x;      // 0..262143
    int r = i >> 9, c = i & 511;
    int tr = r >> 7, tc = c >> 7, rr = r & 127, cc = c & 127;
    if (tr > tc) { int tmp = tr; tr = tc; tc = tmp; tmp = rr; rr = cc; cc = tmp; }
    int tid = tr * 4 + tc - ((tr * (tr + 1)) >> 1);
    const float* src = Gp + ((size_t)tid << 14) + rr * 128 + cc;
    float s = 0.f;
    #pragma unroll
    for (int p = 0; p < 32; ++p) s += src[(size_t)p * 163840];
    G[i] = s;
}

// ===== kD: protos, tiled for G-reuse: 13 class-groups x 16 col-panels =====
__global__ __launch_bounds__(256) void kD(const float* __restrict__ u_arr,
        const float* __restrict__ v_arr, const int* __restrict__ cnt,
        const float* __restrict__ G, float* __restrict__ out) {
    __shared__ float us[8][512];
    int g = blockIdx.x >> 4;            // 0..12
    int panel = blockIdx.x & 15;        // 0..15
    int t = threadIdx.x;
    for (int idx = t; idx < 8 * 512; idx += 256) {
        int ci = idx >> 9, k = idx & 511;
        int cc = g * 8 + ci;
        us[ci][k] = (cc < C_CLS) ? u_arr[(size_t)cc * D_DIM + k] : 0.f;
    }
    __syncthreads();
    int ci = t >> 5, cj = t & 31;
    int c = g * 8 + ci;
    int j = panel * 32 + cj;
    float acc = 0.f;
    #pragma unroll 8
    for (int k = 0; k < D_DIM; ++k)
        acc += us[ci][k] * G[(size_t)k * D_DIM + j];
    if (c < C_CLS) {
        int n = cnt[c];
        float s = (n > 0) ? 1.0f / (float)n : 0.0f;
        out[(size_t)c * D_DIM + j] = (v_arr[(size_t)c * D_DIM + j] + acc) * s;
    }
}

// ===== kE: inter[i,j,:] = proto[j] - proto[i]; 4 pairs/block =====
__global__ __launch_bounds__(256) void kE(const float* __restrict__ proto,
                                          float* __restrict__ inter) {
    int pair = blockIdx.x * 4 + (threadIdx.x >> 6);
    int i = pair / C_CLS;
    int j = pair - i * C_CLS;
    int d = (threadIdx.x & 63) << 3;
    float4 pj0 = *(const float4*)&proto[j * D_DIM + d];
    float4 pj1 = *(const float4*)&proto[j * D_DIM + d + 4];
    float4 pi0 = *(const float4*)&proto[i * D_DIM + d];
    float4 pi1 = *(const float4*)&proto[i * D_DIM + d + 4];
    float4 r0, r1;
    r0.x = pj0.x - pi0.x; r0.y = pj0.y - pi0.y; r0.z = pj0.z - pi0.z; r0.w = pj0.w - pi0.w;
    r1.x = pj1.x - pi1.x; r1.y = pj1.y - pi1.y; r1.z = pj1.z - pi1.z; r1.w = pj1.w - pi1.w;
    *(float4*)&inter[(size_t)pair * D_DIM + d]     = r0;
    *(float4*)&inter[(size_t)pair * D_DIM + d + 4] = r1;
}

extern "C" void kernel_launch(void* const* d_in, const int* in_sizes, int n_in,
                              void* d_out, int out_size, void* d_ws, size_t ws_size,
                              hipStream_t stream) {
    const float* x      = (const float*)d_in[0];   // [8192, 512]
    const float* logits = (const float*)d_in[1];   // [8192, 100]
    float* out = (float*)d_out;
    float* ws  = (float*)d_ws;
    float* G     = ws + WS_G;
    float* Gp    = ws + WS_GP;
    float* inv   = ws + WS_INV;
    float* wv    = ws + WS_WV;
    int*   cls   = (int*)(ws + WS_CLS);
    int*   cnt   = (int*)(ws + WS_CNT);
    int*   offs  = (int*)(ws + WS_OFFS);
    int*   order = (int*)(ws + WS_ORDER);
    float* u_arr = ws + WS_U;
    float* v_arr = ws + WS_V;
    u16* zth = (u16*)(ws + WS_ZTH);

    kA<<<1536, 256, 0, stream>>>(logits, x, wv, cls, inv, zth);
    kB<<<1, 1024, 0, stream>>>(cls, cnt, offs, order);
    kC<<<1120, 256, 0, stream>>>(zth, x, inv, wv, order, offs, cnt, Gp, u_arr, v_arr);
    kR<<<1024, 256, 0, stream>>>(Gp, G);
    kD<<<208, 256, 0, stream>>>(u_arr, v_arr, cnt, G, out);
    kE<<<C_CLS * C_CLS / 4, 256, 0, stream>>>(out, out + C_CLS * D_DIM);
}